// Round 6
// baseline (315.021 us; speedup 1.0000x reference)
//
#include <hip/hip_runtime.h>
#include <stdint.h>

#define L_SEQ 1024
#define NHEAD 32
#define NPREV 28
#define HDIM  64
#define HID   2048
#define NPROJ 2560  // 2048 q + 256 k + 256 v

typedef __bf16 bf16_t;
typedef bf16_t bf16x8 __attribute__((ext_vector_type(8)));
typedef float  f32x4  __attribute__((ext_vector_type(4)));

__device__ __forceinline__ ushort f2bf(float x) {
    union { float f; uint32_t u; } v; v.f = x;
    uint32_t r = v.u + 0x7fffu + ((v.u >> 16) & 1u);
    return (ushort)(r >> 16);
}
__device__ __forceinline__ ushort f2bf_t(float x) {  // truncate (cheap, P in [0,~128])
    union { float f; uint32_t u; } v; v.f = x;
    return (ushort)(v.u >> 16);
}
__device__ __forceinline__ float bf2f(ushort u) {
    union { uint32_t u; float f; } v; v.u = ((uint32_t)u) << 16; return v.f;
}
__device__ __forceinline__ void cvt8(float* dst, uint4 u) {
    union { uint32_t u; float f; } t;
    t.u = u.x << 16;         dst[0] = t.f;
    t.u = u.x & 0xffff0000u; dst[1] = t.f;
    t.u = u.y << 16;         dst[2] = t.f;
    t.u = u.y & 0xffff0000u; dst[3] = t.f;
    t.u = u.z << 16;         dst[4] = t.f;
    t.u = u.z & 0xffff0000u; dst[5] = t.f;
    t.u = u.w << 16;         dst[6] = t.f;
    t.u = u.w & 0xffff0000u; dst[7] = t.f;
}

#define GLB(p) ((const __attribute__((address_space(1))) void*)(p))
#define LDS(p) ((__attribute__((address_space(3))) void*)(p))

// ---------------- merged fp32 -> bf16 conversion ----------------
__global__ void cvt_all(const float* __restrict__ s0, const float* __restrict__ s1,
                        const float* __restrict__ s2, const float* __restrict__ s3,
                        const float* __restrict__ s4,
                        ushort* __restrict__ d0, ushort* __restrict__ d1,
                        ushort* __restrict__ d2, ushort* __restrict__ d3,
                        ushort* __restrict__ d4) {
    int blk = blockIdx.x;
    const float* src; ushort* dst; int idx;
    if      (blk < 4096) { src = s0; dst = d0; idx = blk; }
    else if (blk < 8192) { src = s1; dst = d1; idx = blk - 4096; }
    else if (blk < 8704) { src = s2; dst = d2; idx = blk - 8192; }
    else if (blk < 9216) { src = s3; dst = d3; idx = blk - 8704; }
    else                 { src = s4; dst = d4; idx = blk - 9216; }
    int i = idx * 256 + threadIdx.x;
    float4 v = ((const float4*)src)[i];
    ushort4 o;
    o.x = f2bf(v.x); o.y = f2bf(v.y); o.z = f2bf(v.z); o.w = f2bf(v.w);
    ((ushort4*)dst)[i] = o;
}

// ---------------- bf16 GEMM: C[M,N] = A[M,K] * B[N,K]^T ----------------
// 64x128 tile, 4 waves 2x2 (wave = 32x64), global_load_lds width-16,
// LDS double-buffer, single barrier per K-iter. 4 blocks/CU.
template <bool OUT_BF16>
__global__ __launch_bounds__(256, 4) void gemm_bt(const ushort* __restrict__ A,
                                                  const ushort* __restrict__ B,
                                                  void* __restrict__ C,
                                                  int M, int N, int K) {
    __shared__ __align__(16) ushort Ash[2 * 64 * 32];
    __shared__ __align__(16) ushort Bsh[2 * 128 * 32];
    const int tid  = threadIdx.x;
    const int lane = tid & 63;
    const int wave = tid >> 6;
    const int quad = lane >> 4;
    const int l16  = lane & 15;
    const int m0 = blockIdx.y * 64;
    const int n0 = blockIdx.x * 128;
    const int wm = (wave >> 1) * 32;
    const int wn = (wave & 1) * 64;

    f32x4 acc[2][4] = {};

    const ushort* Ag = A + (long)(m0 + (tid >> 2)) * K + (tid & 3) * 8;
    const ushort* Bg = B + (long)(n0 + (tid >> 2)) * K + (tid & 3) * 8;
    const int woff = wave * 512;

    __builtin_amdgcn_global_load_lds(GLB(Ag),           LDS(Ash + woff),        16, 0, 0);
    __builtin_amdgcn_global_load_lds(GLB(Bg),           LDS(Bsh + woff),        16, 0, 0);
    __builtin_amdgcn_global_load_lds(GLB(Bg + 64L * K), LDS(Bsh + 2048 + woff), 16, 0, 0);

    int cur = 0;
    for (int k0 = 0; k0 < K; k0 += 32) {
        __syncthreads();
        if (k0 + 32 < K) {
            const int na = (cur ^ 1) * 2048;
            const int nb = (cur ^ 1) * 4096;
            __builtin_amdgcn_global_load_lds(GLB(Ag + k0 + 32),           LDS(Ash + na + woff),        16, 0, 0);
            __builtin_amdgcn_global_load_lds(GLB(Bg + k0 + 32),           LDS(Bsh + nb + woff),        16, 0, 0);
            __builtin_amdgcn_global_load_lds(GLB(Bg + 64L * K + k0 + 32), LDS(Bsh + nb + 2048 + woff), 16, 0, 0);
        }
        const ushort* As = Ash + cur * 2048;
        const ushort* Bs = Bsh + cur * 4096;
        bf16x8 af[2], bf[4];
#pragma unroll
        for (int i = 0; i < 2; i++)
            af[i] = *(const bf16x8*)(As + (wm + i * 16 + l16) * 32 + quad * 8);
#pragma unroll
        for (int i = 0; i < 4; i++)
            bf[i] = *(const bf16x8*)(Bs + (wn + i * 16 + l16) * 32 + quad * 8);
#pragma unroll
        for (int mi = 0; mi < 2; mi++)
#pragma unroll
            for (int ni = 0; ni < 4; ni++)
                acc[mi][ni] = __builtin_amdgcn_mfma_f32_16x16x32_bf16(af[mi], bf[ni], acc[mi][ni], 0, 0, 0);
        cur ^= 1;
    }
#pragma unroll
    for (int mi = 0; mi < 2; mi++)
#pragma unroll
        for (int ni = 0; ni < 4; ni++)
#pragma unroll
            for (int r = 0; r < 4; r++) {
                int m = m0 + wm + mi * 16 + quad * 4 + r;
                int n = n0 + wn + ni * 16 + l16;
                float v = acc[mi][ni][r];
                if (OUT_BF16) ((ushort*)C)[(long)m * N + n] = f2bf(v);
                else          ((float*)C)[(long)m * N + n]  = v;
            }
}

// ---------------- prep: DeCAN gather + RoPE + V transpose fused ----------------
__global__ __launch_bounds__(256) void prep_qkv(const ushort* __restrict__ proj,
                                                const float* __restrict__ prev_k,
                                                const float* __restrict__ prev_v,
                                                const float* __restrict__ cosb,
                                                const float* __restrict__ sinb,
                                                ushort* __restrict__ Qr,
                                                ushort* __restrict__ Kr,
                                                ushort* __restrict__ Vt) {
    __shared__ __align__(16) ushort T[64 * 72];
    const int t  = threadIdx.x;
    const int l0 = blockIdx.x * 64;
    const int bh = blockIdx.y;
    const int b  = bh >> 5, h = bh & 31;
    const int r  = t >> 2;
    const int c0 = (t & 3) * 8;
    const int l  = l0 + r;
    const long prow = ((long)(b * L_SEQ + l)) * NPROJ;
    const long base = (long)bh * (L_SEQ * HDIM);

    float cv[8], sv[8];
    *(float4*)(cv)     = *(const float4*)(cosb + l * 64 + c0);
    *(float4*)(cv + 4) = *(const float4*)(cosb + l * 64 + c0 + 4);
    *(float4*)(sv)     = *(const float4*)(sinb + l * 64 + c0);
    *(float4*)(sv + 4) = *(const float4*)(sinb + l * 64 + c0 + 4);

    const float SC = 0.125f * 1.44269504f;  // scale * log2(e)

    // ---- Q ----
    {
        float xl[8], xh[8];
        cvt8(xl, *(const uint4*)(proj + prow + h * 64 + c0));
        cvt8(xh, *(const uint4*)(proj + prow + h * 64 + c0 + 32));
        ushort ol[8], oh[8];
#pragma unroll
        for (int i = 0; i < 8; i++) {
            ol[i] = f2bf((xl[i] * cv[i] - xh[i] * sv[i]) * SC);
            oh[i] = f2bf((xh[i] * cv[i] + xl[i] * sv[i]) * SC);
        }
        ushort* q = Qr + base + (long)l * 64;
        *(uint4*)(q + c0)      = *(uint4*)ol;
        *(uint4*)(q + c0 + 32) = *(uint4*)oh;
    }
    // ---- K ----
    {
        float xl[8], xh[8];
        if (h < NPREV) {
            const float* pk = prev_k + (((long)b * NPREV + h) * L_SEQ + l) * 64;
            *(float4*)(xl)     = *(const float4*)(pk + c0);
            *(float4*)(xl + 4) = *(const float4*)(pk + c0 + 4);
            *(float4*)(xh)     = *(const float4*)(pk + c0 + 32);
            *(float4*)(xh + 4) = *(const float4*)(pk + c0 + 36);
        } else {
            cvt8(xl, *(const uint4*)(proj + prow + HID + (h - NPREV) * 64 + c0));
            cvt8(xh, *(const uint4*)(proj + prow + HID + (h - NPREV) * 64 + c0 + 32));
        }
        ushort ol[8], oh[8];
#pragma unroll
        for (int i = 0; i < 8; i++) {
            ol[i] = f2bf(xl[i] * cv[i] - xh[i] * sv[i]);
            oh[i] = f2bf(xh[i] * cv[i] + xl[i] * sv[i]);
        }
        ushort* k = Kr + base + (long)l * 64;
        *(uint4*)(k + c0)      = *(uint4*)ol;
        *(uint4*)(k + c0 + 32) = *(uint4*)oh;
    }
    // ---- V (transpose via LDS) ----
    {
        float xl[8], xh[8];
        if (h < NPREV) {
            const float* pv = prev_v + (((long)b * NPREV + h) * L_SEQ + l) * 64;
            *(float4*)(xl)     = *(const float4*)(pv + c0);
            *(float4*)(xl + 4) = *(const float4*)(pv + c0 + 4);
            *(float4*)(xh)     = *(const float4*)(pv + c0 + 32);
            *(float4*)(xh + 4) = *(const float4*)(pv + c0 + 36);
        } else {
            cvt8(xl, *(const uint4*)(proj + prow + HID + 256 + (h - NPREV) * 64 + c0));
            cvt8(xh, *(const uint4*)(proj + prow + HID + 256 + (h - NPREV) * 64 + c0 + 32));
        }
#pragma unroll
        for (int i = 0; i < 8; i++) {
            T[(c0 + i) * 72 + r]      = f2bf(xl[i]);
            T[(c0 + 32 + i) * 72 + r] = f2bf(xh[i]);
        }
    }
    __syncthreads();
    {
        const int lc = (t & 3) * 16;
        uint4 o0 = *(const uint4*)(T + r * 72 + lc);
        uint4 o1 = *(const uint4*)(T + r * 72 + lc + 8);
        ushort* og = Vt + base + (long)r * L_SEQ + l0 + lc;
        *(uint4*)og       = o0;
        *(uint4*)(og + 8) = o1;
    }
}

// ---------------- MFMA flash attention v4: shared-LDS K/V, dbuf, 1 barrier/iter ----------
// grid (8, 64 bh), 256 threads = 4 waves. Wave w owns q-rows
// [qbase + w*16, +16) (m0) and [qbase+64+w*16, +16) (m1), qbase = (7-bx)*128.
// K/V staged in shared LDS (dbuf, reg-prefetch); fixed-max exp2 softmax
// (Q carries 0.125*log2e; logits bounded so no running max needed);
// P via wave-private LDS; deferred l-reduction in epilogue.
#define KP 68
__global__ __launch_bounds__(256, 3) void attn_mfma(const ushort* __restrict__ Qr,
                                                    const ushort* __restrict__ Kr,
                                                    const ushort* __restrict__ Vt,
                                                    ushort* __restrict__ Oa) {
    __shared__ __align__(16) ushort Ksh[2][64 * KP];
    __shared__ __align__(16) ushort Vsh[2][64 * KP];
    __shared__ __align__(16) ushort Psh[4][2][16 * KP];

    const int tid  = threadIdx.x;
    const int lane = tid & 63;
    const int wave = tid >> 6;
    const int quad = lane >> 4;
    const int l16  = lane & 15;
    const int bh   = blockIdx.y;
    const int qt   = 7 - (int)blockIdx.x;      // heavy-first
    const int qbase = qt * 128;
    const long base = (long)bh * (L_SEQ * HDIM);

    // Q A-frags: m0 rows qbase+wave*16+l16 ; m1 rows +64
    bf16x8 qf0[2], qf1[2];
    {
        const ushort* q0p = Qr + base + (long)(qbase + wave * 16 + l16) * HDIM + quad * 8;
#pragma unroll
        for (int ks = 0; ks < 2; ks++) {
            qf0[ks] = *(const bf16x8*)(q0p + ks * 32);
            qf1[ks] = *(const bf16x8*)(q0p + 64 * HDIM + ks * 32);
        }
    }
    float lr0[4] = {}, lr1[4] = {};
    f32x4 o0[4] = {}, o1[4] = {};

    ushort* P0 = &Psh[wave][0][0];
    ushort* P1 = &Psh[wave][1][0];
    const int kvend = qbase + 64;
    const int mrow0 = wave * 16 + quad * 4;    // q-row offset within the 64-row window

    const int srow = tid >> 2;                 // staging row 0..63
    const int scol = (tid & 3) * 16;

    // stage tile 0 into buf 0
    {
        const ushort* kg = Kr + base + (long)srow * HDIM + scol;
        const ushort* vg = Vt + base + (long)srow * L_SEQ + scol;
        uint4 k0v = *(const uint4*)kg, k1v = *(const uint4*)(kg + 8);
        uint4 v0v = *(const uint4*)vg, v1v = *(const uint4*)(vg + 8);
        *(uint4*)(Ksh[0] + srow * KP + scol)     = k0v;
        *(uint4*)(Ksh[0] + srow * KP + scol + 8) = k1v;
        *(uint4*)(Vsh[0] + srow * KP + scol)     = v0v;
        *(uint4*)(Vsh[0] + srow * KP + scol + 8) = v1v;
    }
    __syncthreads();

    int cur = 0;
    for (int kv0 = 0; kv0 <= kvend; kv0 += 64) {
        const bool havenext = (kv0 + 64 <= kvend);
        const bool skip0 = (kv0 > qbase);      // last tile: m0 fully masked
        const bool diag0 = (kv0 == qbase);
        const bool diag1 = (kv0 == kvend);

        // issue next-tile global loads early; latency hides under compute
        uint4 nk0, nk1, nv0, nv1;
        if (havenext) {
            const ushort* kg = Kr + base + (long)(kv0 + 64 + srow) * HDIM + scol;
            const ushort* vg = Vt + base + (long)srow * L_SEQ + kv0 + 64 + scol;
            nk0 = *(const uint4*)kg; nk1 = *(const uint4*)(kg + 8);
            nv0 = *(const uint4*)vg; nv1 = *(const uint4*)(vg + 8);
        }

        const ushort* Ks = Ksh[cur];
        const ushort* Vs = Vsh[cur];

        // S = Q K^T
        f32x4 s0[4] = {}, s1[4] = {};
#pragma unroll
        for (int ks = 0; ks < 2; ks++)
#pragma unroll
            for (int nt = 0; nt < 4; nt++) {
                bf16x8 kf = *(const bf16x8*)(Ks + (nt * 16 + l16) * KP + ks * 32 + quad * 8);
                if (!skip0) s0[nt] = __builtin_amdgcn_mfma_f32_16x16x32_bf16(qf0[ks], kf, s0[nt], 0, 0, 0);
                s1[nt] = __builtin_amdgcn_mfma_f32_16x16x32_bf16(qf1[ks], kf, s1[nt], 0, 0, 0);
            }

        // fixed-max softmax: p = exp2(s); causal mask on diagonal tiles
#pragma unroll
        for (int nt = 0; nt < 4; nt++) {
            const int col = nt * 16 + l16;
#pragma unroll
            for (int r = 0; r < 4; r++) {
                const int prow = quad * 4 + r;
                const int grow = mrow0 + r;
                if (!skip0) {
                    float p = __builtin_exp2f(s0[nt][r]);
                    if (diag0 && col > grow) p = 0.f;
                    lr0[r] += p;
                    P0[prow * KP + col] = f2bf_t(p);
                }
                float p1 = __builtin_exp2f(s1[nt][r]);
                if (diag1 && col > grow) p1 = 0.f;
                lr1[r] += p1;
                P1[prow * KP + col] = f2bf_t(p1);
            }
        }

        // PV (compiler inserts lgkmcnt between P writes and these reads)
#pragma unroll
        for (int ks = 0; ks < 2; ks++) {
            bf16x8 pf0 = *(const bf16x8*)(P0 + l16 * KP + ks * 32 + quad * 8);
            bf16x8 pf1 = *(const bf16x8*)(P1 + l16 * KP + ks * 32 + quad * 8);
#pragma unroll
            for (int nt = 0; nt < 4; nt++) {
                bf16x8 vf = *(const bf16x8*)(Vs + (nt * 16 + l16) * KP + ks * 32 + quad * 8);
                if (!skip0) o0[nt] = __builtin_amdgcn_mfma_f32_16x16x32_bf16(pf0, vf, o0[nt], 0, 0, 0);
                o1[nt] = __builtin_amdgcn_mfma_f32_16x16x32_bf16(pf1, vf, o1[nt], 0, 0, 0);
            }
        }

        if (havenext) {   // write prefetched tile into the other buffer
            ushort* Kd = Ksh[cur ^ 1];
            ushort* Vd = Vsh[cur ^ 1];
            *(uint4*)(Kd + srow * KP + scol)     = nk0;
            *(uint4*)(Kd + srow * KP + scol + 8) = nk1;
            *(uint4*)(Vd + srow * KP + scol)     = nv0;
            *(uint4*)(Vd + srow * KP + scol + 8) = nv1;
            __syncthreads();   // single barrier/iter: buf^1 ready, buf reads done
        }
        cur ^= 1;
    }

    // epilogue: reduce l over 16 lanes sharing each row, normalize, store
    const int b = bh >> 5, h = bh & 31;
#pragma unroll
    for (int r = 0; r < 4; r++) {
        float a = lr0[r], c = lr1[r];
        a += __shfl_xor(a, 1); a += __shfl_xor(a, 2); a += __shfl_xor(a, 4); a += __shfl_xor(a, 8);
        c += __shfl_xor(c, 1); c += __shfl_xor(c, 2); c += __shfl_xor(c, 4); c += __shfl_xor(c, 8);
        float ia = 1.f / a, ic = 1.f / c;
        long row0 = (long)(b * L_SEQ + qbase + wave * 16 + quad * 4 + r) * HID + h * 64;
        long row1 = row0 + 64L * HID;
#pragma unroll
        for (int nt = 0; nt < 4; nt++) {
            Oa[row0 + nt * 16 + l16] = f2bf(o0[nt][r] * ia);
            Oa[row1 + nt * 16 + l16] = f2bf(o1[nt][r] * ic);
        }
    }
}

// ---------------- host launch ----------------
extern "C" void kernel_launch(void* const* d_in, const int* in_sizes, int n_in,
                              void* d_out, int out_size, void* d_ws, size_t ws_size,
                              hipStream_t stream) {
    const float* hs     = (const float*)d_in[0];
    const float* prev_k = (const float*)d_in[1];
    const float* prev_v = (const float*)d_in[2];
    const float* Wq     = (const float*)d_in[3];
    const float* Wk     = (const float*)d_in[4];
    const float* Wv     = (const float*)d_in[5];
    const float* Wo     = (const float*)d_in[6];
    const float* cosb   = (const float*)d_in[7];
    const float* sinb   = (const float*)d_in[8];
    float* out = (float*)d_out;

    ushort* hs_bf   = (ushort*)d_ws;                 // 2048*2048
    ushort* wqkv_bf = hs_bf + 2048L * 2048;          // 2560*2048
    ushort* wo_bf   = wqkv_bf + 2560L * 2048;        // 2048*2048
    ushort* proj    = wo_bf + 2048L * 2048;          // 2048*2560
    ushort* Qr      = proj + 2048L * 2560;           // 2*32*1024*64
    ushort* Kr      = Qr + 4194304;
    ushort* Vt      = Kr + 4194304;
    ushort* Oa      = Vt + 4194304;                  // 2048*2048

    cvt_all<<<13312, 256, 0, stream>>>(hs, Wq, Wk, Wv, Wo,
                                       hs_bf, wqkv_bf,
                                       wqkv_bf + 2048L * 2048,
                                       wqkv_bf + 2304L * 2048,
                                       wo_bf);
    gemm_bt<true><<<dim3(20, 32), 256, 0, stream>>>(hs_bf, wqkv_bf, proj, 2048, 2560, 2048);
    prep_qkv<<<dim3(16, 64), 256, 0, stream>>>(proj, prev_k, prev_v, cosb, sinb, Qr, Kr, Vt);
    attn_mfma<<<dim3(8, 64), 256, 0, stream>>>(Qr, Kr, Vt, Oa);
    gemm_bt<false><<<dim3(16, 32), 256, 0, stream>>>(Oa, wo_bf, out, 2048, 2048, 2048);
}

// Round 7
// 255.544 us; speedup vs baseline: 1.2327x; 1.2327x over previous
//
#include <hip/hip_runtime.h>
#include <stdint.h>

#define L_SEQ 1024
#define NHEAD 32
#define NPREV 28
#define HDIM  64
#define HID   2048
#define NPROJ 2560  // 2048 q + 256 k + 256 v

typedef __bf16 bf16_t;
typedef bf16_t bf16x8 __attribute__((ext_vector_type(8)));
typedef float  f32x4  __attribute__((ext_vector_type(4)));

__device__ __forceinline__ ushort f2bf(float x) {
    union { float f; uint32_t u; } v; v.f = x;
    uint32_t r = v.u + 0x7fffu + ((v.u >> 16) & 1u);
    return (ushort)(r >> 16);
}
__device__ __forceinline__ ushort f2bf_t(float x) {  // truncate (cheap, P in [0,~150])
    union { float f; uint32_t u; } v; v.f = x;
    return (ushort)(v.u >> 16);
}
__device__ __forceinline__ float bf2f(ushort u) {
    union { uint32_t u; float f; } v; v.u = ((uint32_t)u) << 16; return v.f;
}
__device__ __forceinline__ void cvt8(float* dst, uint4 u) {
    union { uint32_t u; float f; } t;
    t.u = u.x << 16;         dst[0] = t.f;
    t.u = u.x & 0xffff0000u; dst[1] = t.f;
    t.u = u.y << 16;         dst[2] = t.f;
    t.u = u.y & 0xffff0000u; dst[3] = t.f;
    t.u = u.z << 16;         dst[4] = t.f;
    t.u = u.z & 0xffff0000u; dst[5] = t.f;
    t.u = u.w << 16;         dst[6] = t.f;
    t.u = u.w & 0xffff0000u; dst[7] = t.f;
}

#define GLB(p) ((const __attribute__((address_space(1))) void*)(p))
#define LDS(p) ((__attribute__((address_space(3))) void*)(p))

// ---------------- merged fp32 -> bf16 conversion ----------------
__global__ void cvt_all(const float* __restrict__ s0, const float* __restrict__ s1,
                        const float* __restrict__ s2, const float* __restrict__ s3,
                        const float* __restrict__ s4,
                        ushort* __restrict__ d0, ushort* __restrict__ d1,
                        ushort* __restrict__ d2, ushort* __restrict__ d3,
                        ushort* __restrict__ d4) {
    int blk = blockIdx.x;
    const float* src; ushort* dst; int idx;
    if      (blk < 4096) { src = s0; dst = d0; idx = blk; }
    else if (blk < 8192) { src = s1; dst = d1; idx = blk - 4096; }
    else if (blk < 8704) { src = s2; dst = d2; idx = blk - 8192; }
    else if (blk < 9216) { src = s3; dst = d3; idx = blk - 8704; }
    else                 { src = s4; dst = d4; idx = blk - 9216; }
    int i = idx * 256 + threadIdx.x;
    float4 v = ((const float4*)src)[i];
    ushort4 o;
    o.x = f2bf(v.x); o.y = f2bf(v.y); o.z = f2bf(v.z); o.w = f2bf(v.w);
    ((ushort4*)dst)[i] = o;
}

// ---------------- bf16 GEMM: C[M,N] = A[M,K] * B[N,K]^T ----------------
// 64x128 tile, 4 waves 2x2 (wave = 32x64), global_load_lds width-16,
// LDS double-buffer, single barrier per K-iter. 4 blocks/CU.
template <bool OUT_BF16>
__global__ __launch_bounds__(256, 4) void gemm_bt(const ushort* __restrict__ A,
                                                  const ushort* __restrict__ B,
                                                  void* __restrict__ C,
                                                  int M, int N, int K) {
    __shared__ __align__(16) ushort Ash[2 * 64 * 32];
    __shared__ __align__(16) ushort Bsh[2 * 128 * 32];
    const int tid  = threadIdx.x;
    const int lane = tid & 63;
    const int wave = tid >> 6;
    const int quad = lane >> 4;
    const int l16  = lane & 15;
    const int m0 = blockIdx.y * 64;
    const int n0 = blockIdx.x * 128;
    const int wm = (wave >> 1) * 32;
    const int wn = (wave & 1) * 64;

    f32x4 acc[2][4] = {};

    const ushort* Ag = A + (long)(m0 + (tid >> 2)) * K + (tid & 3) * 8;
    const ushort* Bg = B + (long)(n0 + (tid >> 2)) * K + (tid & 3) * 8;
    const int woff = wave * 512;

    __builtin_amdgcn_global_load_lds(GLB(Ag),           LDS(Ash + woff),        16, 0, 0);
    __builtin_amdgcn_global_load_lds(GLB(Bg),           LDS(Bsh + woff),        16, 0, 0);
    __builtin_amdgcn_global_load_lds(GLB(Bg + 64L * K), LDS(Bsh + 2048 + woff), 16, 0, 0);

    int cur = 0;
    for (int k0 = 0; k0 < K; k0 += 32) {
        __syncthreads();
        if (k0 + 32 < K) {
            const int na = (cur ^ 1) * 2048;
            const int nb = (cur ^ 1) * 4096;
            __builtin_amdgcn_global_load_lds(GLB(Ag + k0 + 32),           LDS(Ash + na + woff),        16, 0, 0);
            __builtin_amdgcn_global_load_lds(GLB(Bg + k0 + 32),           LDS(Bsh + nb + woff),        16, 0, 0);
            __builtin_amdgcn_global_load_lds(GLB(Bg + 64L * K + k0 + 32), LDS(Bsh + nb + 2048 + woff), 16, 0, 0);
        }
        const ushort* As = Ash + cur * 2048;
        const ushort* Bs = Bsh + cur * 4096;
        bf16x8 af[2], bf[4];
#pragma unroll
        for (int i = 0; i < 2; i++)
            af[i] = *(const bf16x8*)(As + (wm + i * 16 + l16) * 32 + quad * 8);
#pragma unroll
        for (int i = 0; i < 4; i++)
            bf[i] = *(const bf16x8*)(Bs + (wn + i * 16 + l16) * 32 + quad * 8);
#pragma unroll
        for (int mi = 0; mi < 2; mi++)
#pragma unroll
            for (int ni = 0; ni < 4; ni++)
                acc[mi][ni] = __builtin_amdgcn_mfma_f32_16x16x32_bf16(af[mi], bf[ni], acc[mi][ni], 0, 0, 0);
        cur ^= 1;
    }
#pragma unroll
    for (int mi = 0; mi < 2; mi++)
#pragma unroll
        for (int ni = 0; ni < 4; ni++)
#pragma unroll
            for (int r = 0; r < 4; r++) {
                int m = m0 + wm + mi * 16 + quad * 4 + r;
                int n = n0 + wn + ni * 16 + l16;
                float v = acc[mi][ni][r];
                if (OUT_BF16) ((ushort*)C)[(long)m * N + n] = f2bf(v);
                else          ((float*)C)[(long)m * N + n]  = v;
            }
}

// ---------------- prep: DeCAN gather + RoPE + V transpose fused ----------------
__global__ __launch_bounds__(256) void prep_qkv(const ushort* __restrict__ proj,
                                                const float* __restrict__ prev_k,
                                                const float* __restrict__ prev_v,
                                                const float* __restrict__ cosb,
                                                const float* __restrict__ sinb,
                                                ushort* __restrict__ Qr,
                                                ushort* __restrict__ Kr,
                                                ushort* __restrict__ Vt) {
    __shared__ __align__(16) ushort T[64 * 72];
    const int t  = threadIdx.x;
    const int l0 = blockIdx.x * 64;
    const int bh = blockIdx.y;
    const int b  = bh >> 5, h = bh & 31;
    const int r  = t >> 2;
    const int c0 = (t & 3) * 8;
    const int l  = l0 + r;
    const long prow = ((long)(b * L_SEQ + l)) * NPROJ;
    const long base = (long)bh * (L_SEQ * HDIM);

    float cv[8], sv[8];
    *(float4*)(cv)     = *(const float4*)(cosb + l * 64 + c0);
    *(float4*)(cv + 4) = *(const float4*)(cosb + l * 64 + c0 + 4);
    *(float4*)(sv)     = *(const float4*)(sinb + l * 64 + c0);
    *(float4*)(sv + 4) = *(const float4*)(sinb + l * 64 + c0 + 4);

    const float SC = 0.125f * 1.44269504f;  // scale * log2(e)

    // ---- Q ----
    {
        float xl[8], xh[8];
        cvt8(xl, *(const uint4*)(proj + prow + h * 64 + c0));
        cvt8(xh, *(const uint4*)(proj + prow + h * 64 + c0 + 32));
        ushort ol[8], oh[8];
#pragma unroll
        for (int i = 0; i < 8; i++) {
            ol[i] = f2bf((xl[i] * cv[i] - xh[i] * sv[i]) * SC);
            oh[i] = f2bf((xh[i] * cv[i] + xl[i] * sv[i]) * SC);
        }
        ushort* q = Qr + base + (long)l * 64;
        *(uint4*)(q + c0)      = *(uint4*)ol;
        *(uint4*)(q + c0 + 32) = *(uint4*)oh;
    }
    // ---- K ----
    {
        float xl[8], xh[8];
        if (h < NPREV) {
            const float* pk = prev_k + (((long)b * NPREV + h) * L_SEQ + l) * 64;
            *(float4*)(xl)     = *(const float4*)(pk + c0);
            *(float4*)(xl + 4) = *(const float4*)(pk + c0 + 4);
            *(float4*)(xh)     = *(const float4*)(pk + c0 + 32);
            *(float4*)(xh + 4) = *(const float4*)(pk + c0 + 36);
        } else {
            cvt8(xl, *(const uint4*)(proj + prow + HID + (h - NPREV) * 64 + c0));
            cvt8(xh, *(const uint4*)(proj + prow + HID + (h - NPREV) * 64 + c0 + 32));
        }
        ushort ol[8], oh[8];
#pragma unroll
        for (int i = 0; i < 8; i++) {
            ol[i] = f2bf(xl[i] * cv[i] - xh[i] * sv[i]);
            oh[i] = f2bf(xh[i] * cv[i] + xl[i] * sv[i]);
        }
        ushort* k = Kr + base + (long)l * 64;
        *(uint4*)(k + c0)      = *(uint4*)ol;
        *(uint4*)(k + c0 + 32) = *(uint4*)oh;
    }
    // ---- V (transpose via LDS) ----
    {
        float xl[8], xh[8];
        if (h < NPREV) {
            const float* pv = prev_v + (((long)b * NPREV + h) * L_SEQ + l) * 64;
            *(float4*)(xl)     = *(const float4*)(pv + c0);
            *(float4*)(xl + 4) = *(const float4*)(pv + c0 + 4);
            *(float4*)(xh)     = *(const float4*)(pv + c0 + 32);
            *(float4*)(xh + 4) = *(const float4*)(pv + c0 + 36);
        } else {
            cvt8(xl, *(const uint4*)(proj + prow + HID + 256 + (h - NPREV) * 64 + c0));
            cvt8(xh, *(const uint4*)(proj + prow + HID + 256 + (h - NPREV) * 64 + c0 + 32));
        }
#pragma unroll
        for (int i = 0; i < 8; i++) {
            T[(c0 + i) * 72 + r]      = f2bf(xl[i]);
            T[(c0 + 32 + i) * 72 + r] = f2bf(xh[i]);
        }
    }
    __syncthreads();
    {
        const int lc = (t & 3) * 16;
        uint4 o0 = *(const uint4*)(T + r * 72 + lc);
        uint4 o1 = *(const uint4*)(T + r * 72 + lc + 8);
        ushort* og = Vt + base + (long)r * L_SEQ + l0 + lc;
        *(uint4*)og       = o0;
        *(uint4*)(og + 8) = o1;
    }
}

// ---------------- MFMA flash attention v5: R3 structure + fixed-max softmax --------
// grid (16, 64 bh), 256 thr = 4 waves, 64 q-rows/block (16/wave), kv tiles 64.
// Shared-LDS K/V staging with register prefetch (2 barriers/iter — proven best R3).
// Fixed-max exp2 softmax (Q carries 0.125*log2e; logits bounded) + deferred
// l-reduction (validated R5/R6). P via wave-private LDS.
#define KP 68
__global__ __launch_bounds__(256, 4) void attn_mfma(const ushort* __restrict__ Qr,
                                                    const ushort* __restrict__ Kr,
                                                    const ushort* __restrict__ Vt,
                                                    ushort* __restrict__ Oa) {
    __shared__ __align__(16) ushort Ksh[64 * KP];
    __shared__ __align__(16) ushort Vsh[64 * KP];
    __shared__ __align__(16) ushort Psh[4][16 * KP];

    const int tid  = threadIdx.x;
    const int lane = tid & 63;
    const int wave = tid >> 6;
    const int quad = lane >> 4;
    const int l16  = lane & 15;
    const int bh   = blockIdx.y;
    const int q0   = (15 - (int)blockIdx.x) * 64;  // heavy blocks first
    const long base = (long)bh * (L_SEQ * HDIM);

    bf16x8 qf0, qf1;
    {
        const ushort* qp = Qr + base + (long)(q0 + wave * 16 + l16) * HDIM + quad * 8;
        qf0 = *(const bf16x8*)qp;
        qf1 = *(const bf16x8*)(qp + 32);
    }
    float lr[4] = {};            // per-lane partial row sums (deferred reduce)
    f32x4 o[4] = {};

    const int srow  = tid >> 2;
    const int scol  = (tid & 3) * 16;
    const int row_l = wave * 16 + quad * 4;   // q-row offset within block

    // prefetch tile 0
    uint4 ka, kb, va, vb;
    {
        const ushort* kg = Kr + base + (long)srow * HDIM + scol;
        ka = *(const uint4*)kg; kb = *(const uint4*)(kg + 8);
        const ushort* vg = Vt + base + (long)srow * L_SEQ + scol;
        va = *(const uint4*)vg; vb = *(const uint4*)(vg + 8);
    }

    for (int kv0 = 0; kv0 <= q0; kv0 += 64) {
        __syncthreads();
        *(uint4*)(Ksh + srow * KP + scol)     = ka;
        *(uint4*)(Ksh + srow * KP + scol + 8) = kb;
        *(uint4*)(Vsh + srow * KP + scol)     = va;
        *(uint4*)(Vsh + srow * KP + scol + 8) = vb;
        __syncthreads();
        if (kv0 + 64 <= q0) {   // prefetch next tile; latency hidden by compute
            const ushort* kg = Kr + base + (long)(kv0 + 64 + srow) * HDIM + scol;
            ka = *(const uint4*)kg; kb = *(const uint4*)(kg + 8);
            const ushort* vg = Vt + base + (long)srow * L_SEQ + kv0 + 64 + scol;
            va = *(const uint4*)vg; vb = *(const uint4*)(vg + 8);
        }

        // S = Q K^T
        f32x4 s[4] = {};
#pragma unroll
        for (int nt = 0; nt < 4; nt++) {
            bf16x8 kf0 = *(const bf16x8*)(Ksh + (nt * 16 + l16) * KP + quad * 8);
            bf16x8 kf1 = *(const bf16x8*)(Ksh + (nt * 16 + l16) * KP + 32 + quad * 8);
            s[nt] = __builtin_amdgcn_mfma_f32_16x16x32_bf16(qf0, kf0, s[nt], 0, 0, 0);
            s[nt] = __builtin_amdgcn_mfma_f32_16x16x32_bf16(qf1, kf1, s[nt], 0, 0, 0);
        }

        // fixed-max softmax: p = exp2(s); diagonal causal mask by select
        const bool diag = (kv0 == q0);
#pragma unroll
        for (int nt = 0; nt < 4; nt++) {
            const int col = nt * 16 + l16;
#pragma unroll
            for (int r = 0; r < 4; r++) {
                float p = __builtin_exp2f(s[nt][r]);
                if (diag && col > row_l + r) p = 0.f;
                lr[r] += p;
                Psh[wave][(quad * 4 + r) * KP + col] = f2bf_t(p);
            }
        }

        // PV (compiler inserts lgkmcnt between P writes and these reads)
#pragma unroll
        for (int ks = 0; ks < 2; ks++) {
            bf16x8 pf = *(const bf16x8*)(&Psh[wave][l16 * KP + ks * 32 + quad * 8]);
#pragma unroll
            for (int nt = 0; nt < 4; nt++) {
                bf16x8 vf = *(const bf16x8*)(Vsh + (nt * 16 + l16) * KP + ks * 32 + quad * 8);
                o[nt] = __builtin_amdgcn_mfma_f32_16x16x32_bf16(pf, vf, o[nt], 0, 0, 0);
            }
        }
    }

    // epilogue: reduce l over the 16 lanes sharing each row, normalize, store
    const int b = bh >> 5, h = bh & 31;
#pragma unroll
    for (int r = 0; r < 4; r++) {
        float a = lr[r];
        a += __shfl_xor(a, 1); a += __shfl_xor(a, 2); a += __shfl_xor(a, 4); a += __shfl_xor(a, 8);
        float inv = 1.f / a;
        long orow = (long)(b * L_SEQ + q0 + wave * 16 + quad * 4 + r) * HID + h * 64;
#pragma unroll
        for (int nt = 0; nt < 4; nt++)
            Oa[orow + nt * 16 + l16] = f2bf(o[nt][r] * inv);
    }
}

// ---------------- host launch ----------------
extern "C" void kernel_launch(void* const* d_in, const int* in_sizes, int n_in,
                              void* d_out, int out_size, void* d_ws, size_t ws_size,
                              hipStream_t stream) {
    const float* hs     = (const float*)d_in[0];
    const float* prev_k = (const float*)d_in[1];
    const float* prev_v = (const float*)d_in[2];
    const float* Wq     = (const float*)d_in[3];
    const float* Wk     = (const float*)d_in[4];
    const float* Wv     = (const float*)d_in[5];
    const float* Wo     = (const float*)d_in[6];
    const float* cosb   = (const float*)d_in[7];
    const float* sinb   = (const float*)d_in[8];
    float* out = (float*)d_out;

    ushort* hs_bf   = (ushort*)d_ws;                 // 2048*2048
    ushort* wqkv_bf = hs_bf + 2048L * 2048;          // 2560*2048
    ushort* wo_bf   = wqkv_bf + 2560L * 2048;        // 2048*2048
    ushort* proj    = wo_bf + 2048L * 2048;          // 2048*2560
    ushort* Qr      = proj + 2048L * 2560;           // 2*32*1024*64
    ushort* Kr      = Qr + 4194304;
    ushort* Vt      = Kr + 4194304;
    ushort* Oa      = Vt + 4194304;                  // 2048*2048

    cvt_all<<<13312, 256, 0, stream>>>(hs, Wq, Wk, Wv, Wo,
                                       hs_bf, wqkv_bf,
                                       wqkv_bf + 2048L * 2048,
                                       wqkv_bf + 2304L * 2048,
                                       wo_bf);
    gemm_bt<true><<<dim3(20, 32), 256, 0, stream>>>(hs_bf, wqkv_bf, proj, 2048, 2560, 2048);
    prep_qkv<<<dim3(16, 64), 256, 0, stream>>>(proj, prev_k, prev_v, cosb, sinb, Qr, Kr, Vt);
    attn_mfma<<<dim3(16, 64), 256, 0, stream>>>(Qr, Kr, Vt, Oa);
    gemm_bt<false><<<dim3(16, 32), 256, 0, stream>>>(Oa, wo_bf, out, 2048, 2048, 2048);
}

// Round 8
// 241.022 us; speedup vs baseline: 1.3070x; 1.0603x over previous
//
#include <hip/hip_runtime.h>
#include <stdint.h>

#define L_SEQ 1024
#define NHEAD 32
#define NPREV 28
#define HDIM  64
#define HID   2048
#define NPROJ 2560  // 2048 q + 256 k + 256 v

typedef __bf16 bf16_t;
typedef bf16_t bf16x8 __attribute__((ext_vector_type(8)));
typedef float  f32x4  __attribute__((ext_vector_type(4)));

__device__ __forceinline__ ushort f2bf(float x) {
    union { float f; uint32_t u; } v; v.f = x;
    uint32_t r = v.u + 0x7fffu + ((v.u >> 16) & 1u);
    return (ushort)(r >> 16);
}
__device__ __forceinline__ ushort f2bf_t(float x) {  // truncate (cheap, P in [0,~150])
    union { float f; uint32_t u; } v; v.f = x;
    return (ushort)(v.u >> 16);
}
__device__ __forceinline__ float bf2f(ushort u) {
    union { uint32_t u; float f; } v; v.u = ((uint32_t)u) << 16; return v.f;
}
__device__ __forceinline__ void cvt8(float* dst, uint4 u) {
    union { uint32_t u; float f; } t;
    t.u = u.x << 16;         dst[0] = t.f;
    t.u = u.x & 0xffff0000u; dst[1] = t.f;
    t.u = u.y << 16;         dst[2] = t.f;
    t.u = u.y & 0xffff0000u; dst[3] = t.f;
    t.u = u.z << 16;         dst[4] = t.f;
    t.u = u.z & 0xffff0000u; dst[5] = t.f;
    t.u = u.w << 16;         dst[6] = t.f;
    t.u = u.w & 0xffff0000u; dst[7] = t.f;
}

#define GLB(p) ((const __attribute__((address_space(1))) void*)(p))
#define LDS(p) ((__attribute__((address_space(3))) void*)(p))

// ---------------- merged fp32 -> bf16 conversion ----------------
__global__ void cvt_all(const float* __restrict__ s0, const float* __restrict__ s1,
                        const float* __restrict__ s2, const float* __restrict__ s3,
                        const float* __restrict__ s4,
                        ushort* __restrict__ d0, ushort* __restrict__ d1,
                        ushort* __restrict__ d2, ushort* __restrict__ d3,
                        ushort* __restrict__ d4) {
    int blk = blockIdx.x;
    const float* src; ushort* dst; int idx;
    if      (blk < 4096) { src = s0; dst = d0; idx = blk; }
    else if (blk < 8192) { src = s1; dst = d1; idx = blk - 4096; }
    else if (blk < 8704) { src = s2; dst = d2; idx = blk - 8192; }
    else if (blk < 9216) { src = s3; dst = d3; idx = blk - 8704; }
    else                 { src = s4; dst = d4; idx = blk - 9216; }
    int i = idx * 256 + threadIdx.x;
    float4 v = ((const float4*)src)[i];
    ushort4 o;
    o.x = f2bf(v.x); o.y = f2bf(v.y); o.z = f2bf(v.z); o.w = f2bf(v.w);
    ((ushort4*)dst)[i] = o;
}

// ---------------- bf16 GEMM: C[M,N] = A[M,K] * B[N,K]^T ----------------
// 64x128 tile, 4 waves 2x2 (wave = 32x64), global_load_lds width-16,
// BK=64, LDS double-buffer (48 KB), single barrier per K-iter.
// XOR-swizzled LDS tiles: lane l stages global colblock (l&3)^((l>>3)&3)
// into its fixed DMA chunk; readers use chunk quad^((l16>>1)&3). Quad's 16
// rows spread over all 8 bank-start positions exactly 2-way (free, m136).
template <bool OUT_BF16>
__global__ __launch_bounds__(256, 3) void gemm_bt(const ushort* __restrict__ A,
                                                  const ushort* __restrict__ B,
                                                  void* __restrict__ C,
                                                  int M, int N, int K) {
    __shared__ __align__(16) ushort Ash[2 * 64 * 64];    // 2 bufs x (2 k-halves x 64x32)
    __shared__ __align__(16) ushort Bsh[2 * 128 * 64];   // 2 bufs x (2 k-halves x 128x32)
    const int tid  = threadIdx.x;
    const int lane = tid & 63;
    const int wave = tid >> 6;
    const int quad = lane >> 4;
    const int l16  = lane & 15;
    const int m0 = blockIdx.y * 64;
    const int n0 = blockIdx.x * 128;
    const int wm = (wave >> 1) * 32;
    const int wn = (wave & 1) * 64;

    f32x4 acc[2][4] = {};

    // swizzled staging source: chunk (row=tid>>2, c=tid&3) holds colblock c^((row>>1)&3)
    const int sb = ((tid & 3) ^ ((tid >> 3) & 3)) * 8;
    const ushort* Ag = A + (long)(m0 + (tid >> 2)) * K + sb;
    const ushort* Bg = B + (long)(n0 + (tid >> 2)) * K + sb;
    const int woff = wave * 512;
    const int swz = (quad ^ ((l16 >> 1) & 3)) * 8;   // reader chunk select

    // preload k=[0,64) into buf 0
    __builtin_amdgcn_global_load_lds(GLB(Ag),                LDS(Ash + woff),               16, 0, 0);
    __builtin_amdgcn_global_load_lds(GLB(Ag + 32),           LDS(Ash + 2048 + woff),        16, 0, 0);
    __builtin_amdgcn_global_load_lds(GLB(Bg),                LDS(Bsh + woff),               16, 0, 0);
    __builtin_amdgcn_global_load_lds(GLB(Bg + 64L * K),      LDS(Bsh + 2048 + woff),        16, 0, 0);
    __builtin_amdgcn_global_load_lds(GLB(Bg + 32),           LDS(Bsh + 4096 + woff),        16, 0, 0);
    __builtin_amdgcn_global_load_lds(GLB(Bg + 64L * K + 32), LDS(Bsh + 4096 + 2048 + woff), 16, 0, 0);

    int cur = 0;
    for (int k0 = 0; k0 < K; k0 += 64) {
        __syncthreads();   // drains vmcnt -> buf[cur] ready
        if (k0 + 64 < K) {
            const int na = (cur ^ 1) * 4096;
            const int nb = (cur ^ 1) * 8192;
            const ushort* Agn = Ag + k0 + 64;
            const ushort* Bgn = Bg + k0 + 64;
            __builtin_amdgcn_global_load_lds(GLB(Agn),                LDS(Ash + na + woff),               16, 0, 0);
            __builtin_amdgcn_global_load_lds(GLB(Agn + 32),           LDS(Ash + na + 2048 + woff),        16, 0, 0);
            __builtin_amdgcn_global_load_lds(GLB(Bgn),                LDS(Bsh + nb + woff),               16, 0, 0);
            __builtin_amdgcn_global_load_lds(GLB(Bgn + 64L * K),      LDS(Bsh + nb + 2048 + woff),        16, 0, 0);
            __builtin_amdgcn_global_load_lds(GLB(Bgn + 32),           LDS(Bsh + nb + 4096 + woff),        16, 0, 0);
            __builtin_amdgcn_global_load_lds(GLB(Bgn + 64L * K + 32), LDS(Bsh + nb + 4096 + 2048 + woff), 16, 0, 0);
        }
        const ushort* As = Ash + cur * 4096;
        const ushort* Bs = Bsh + cur * 8192;
#pragma unroll
        for (int h = 0; h < 2; h++) {
            bf16x8 af[2], bf[4];
#pragma unroll
            for (int i = 0; i < 2; i++)
                af[i] = *(const bf16x8*)(As + h * 2048 + (wm + i * 16 + l16) * 32 + swz);
#pragma unroll
            for (int i = 0; i < 4; i++)
                bf[i] = *(const bf16x8*)(Bs + h * 4096 + (wn + i * 16 + l16) * 32 + swz);
#pragma unroll
            for (int mi = 0; mi < 2; mi++)
#pragma unroll
                for (int ni = 0; ni < 4; ni++)
                    acc[mi][ni] = __builtin_amdgcn_mfma_f32_16x16x32_bf16(af[mi], bf[ni], acc[mi][ni], 0, 0, 0);
        }
        cur ^= 1;
    }
#pragma unroll
    for (int mi = 0; mi < 2; mi++)
#pragma unroll
        for (int ni = 0; ni < 4; ni++)
#pragma unroll
            for (int r = 0; r < 4; r++) {
                int m = m0 + wm + mi * 16 + quad * 4 + r;
                int n = n0 + wn + ni * 16 + l16;
                float v = acc[mi][ni][r];
                if (OUT_BF16) ((ushort*)C)[(long)m * N + n] = f2bf(v);
                else          ((float*)C)[(long)m * N + n]  = v;
            }
}

// ---------------- prep: DeCAN gather + RoPE + V transpose fused ----------------
__global__ __launch_bounds__(256) void prep_qkv(const ushort* __restrict__ proj,
                                                const float* __restrict__ prev_k,
                                                const float* __restrict__ prev_v,
                                                const float* __restrict__ cosb,
                                                const float* __restrict__ sinb,
                                                ushort* __restrict__ Qr,
                                                ushort* __restrict__ Kr,
                                                ushort* __restrict__ Vt) {
    __shared__ __align__(16) ushort T[64 * 72];
    const int t  = threadIdx.x;
    const int l0 = blockIdx.x * 64;
    const int bh = blockIdx.y;
    const int b  = bh >> 5, h = bh & 31;
    const int r  = t >> 2;
    const int c0 = (t & 3) * 8;
    const int l  = l0 + r;
    const long prow = ((long)(b * L_SEQ + l)) * NPROJ;
    const long base = (long)bh * (L_SEQ * HDIM);

    float cv[8], sv[8];
    *(float4*)(cv)     = *(const float4*)(cosb + l * 64 + c0);
    *(float4*)(cv + 4) = *(const float4*)(cosb + l * 64 + c0 + 4);
    *(float4*)(sv)     = *(const float4*)(sinb + l * 64 + c0);
    *(float4*)(sv + 4) = *(const float4*)(sinb + l * 64 + c0 + 4);

    const float SC = 0.125f * 1.44269504f;  // scale * log2(e)

    // ---- Q ----
    {
        float xl[8], xh[8];
        cvt8(xl, *(const uint4*)(proj + prow + h * 64 + c0));
        cvt8(xh, *(const uint4*)(proj + prow + h * 64 + c0 + 32));
        ushort ol[8], oh[8];
#pragma unroll
        for (int i = 0; i < 8; i++) {
            ol[i] = f2bf((xl[i] * cv[i] - xh[i] * sv[i]) * SC);
            oh[i] = f2bf((xh[i] * cv[i] + xl[i] * sv[i]) * SC);
        }
        ushort* q = Qr + base + (long)l * 64;
        *(uint4*)(q + c0)      = *(uint4*)ol;
        *(uint4*)(q + c0 + 32) = *(uint4*)oh;
    }
    // ---- K ----
    {
        float xl[8], xh[8];
        if (h < NPREV) {
            const float* pk = prev_k + (((long)b * NPREV + h) * L_SEQ + l) * 64;
            *(float4*)(xl)     = *(const float4*)(pk + c0);
            *(float4*)(xl + 4) = *(const float4*)(pk + c0 + 4);
            *(float4*)(xh)     = *(const float4*)(pk + c0 + 32);
            *(float4*)(xh + 4) = *(const float4*)(pk + c0 + 36);
        } else {
            cvt8(xl, *(const uint4*)(proj + prow + HID + (h - NPREV) * 64 + c0));
            cvt8(xh, *(const uint4*)(proj + prow + HID + (h - NPREV) * 64 + c0 + 32));
        }
        ushort ol[8], oh[8];
#pragma unroll
        for (int i = 0; i < 8; i++) {
            ol[i] = f2bf(xl[i] * cv[i] - xh[i] * sv[i]);
            oh[i] = f2bf(xh[i] * cv[i] + xl[i] * sv[i]);
        }
        ushort* k = Kr + base + (long)l * 64;
        *(uint4*)(k + c0)      = *(uint4*)ol;
        *(uint4*)(k + c0 + 32) = *(uint4*)oh;
    }
    // ---- V (transpose via LDS) ----
    {
        float xl[8], xh[8];
        if (h < NPREV) {
            const float* pv = prev_v + (((long)b * NPREV + h) * L_SEQ + l) * 64;
            *(float4*)(xl)     = *(const float4*)(pv + c0);
            *(float4*)(xl + 4) = *(const float4*)(pv + c0 + 4);
            *(float4*)(xh)     = *(const float4*)(pv + c0 + 32);
            *(float4*)(xh + 4) = *(const float4*)(pv + c0 + 36);
        } else {
            cvt8(xl, *(const uint4*)(proj + prow + HID + 256 + (h - NPREV) * 64 + c0));
            cvt8(xh, *(const uint4*)(proj + prow + HID + 256 + (h - NPREV) * 64 + c0 + 32));
        }
#pragma unroll
        for (int i = 0; i < 8; i++) {
            T[(c0 + i) * 72 + r]      = f2bf(xl[i]);
            T[(c0 + 32 + i) * 72 + r] = f2bf(xh[i]);
        }
    }
    __syncthreads();
    {
        const int lc = (t & 3) * 16;
        uint4 o0 = *(const uint4*)(T + r * 72 + lc);
        uint4 o1 = *(const uint4*)(T + r * 72 + lc + 8);
        ushort* og = Vt + base + (long)r * L_SEQ + l0 + lc;
        *(uint4*)og       = o0;
        *(uint4*)(og + 8) = o1;
    }
}

// ---------------- MFMA flash attention v5: R3 structure + fixed-max softmax --------
// grid (16, 64 bh), 256 thr = 4 waves, 64 q-rows/block (16/wave), kv tiles 64.
// Shared-LDS K/V staging with register prefetch (2 barriers/iter — proven best R3).
// Fixed-max exp2 softmax (Q carries 0.125*log2e; logits bounded) + deferred
// l-reduction (validated R5/R6). P via wave-private LDS.
#define KP 68
__global__ __launch_bounds__(256, 4) void attn_mfma(const ushort* __restrict__ Qr,
                                                    const ushort* __restrict__ Kr,
                                                    const ushort* __restrict__ Vt,
                                                    ushort* __restrict__ Oa) {
    __shared__ __align__(16) ushort Ksh[64 * KP];
    __shared__ __align__(16) ushort Vsh[64 * KP];
    __shared__ __align__(16) ushort Psh[4][16 * KP];

    const int tid  = threadIdx.x;
    const int lane = tid & 63;
    const int wave = tid >> 6;
    const int quad = lane >> 4;
    const int l16  = lane & 15;
    const int bh   = blockIdx.y;
    const int q0   = (15 - (int)blockIdx.x) * 64;  // heavy blocks first
    const long base = (long)bh * (L_SEQ * HDIM);

    bf16x8 qf0, qf1;
    {
        const ushort* qp = Qr + base + (long)(q0 + wave * 16 + l16) * HDIM + quad * 8;
        qf0 = *(const bf16x8*)qp;
        qf1 = *(const bf16x8*)(qp + 32);
    }
    float lr[4] = {};            // per-lane partial row sums (deferred reduce)
    f32x4 o[4] = {};

    const int srow  = tid >> 2;
    const int scol  = (tid & 3) * 16;
    const int row_l = wave * 16 + quad * 4;   // q-row offset within block

    // prefetch tile 0
    uint4 ka, kb, va, vb;
    {
        const ushort* kg = Kr + base + (long)srow * HDIM + scol;
        ka = *(const uint4*)kg; kb = *(const uint4*)(kg + 8);
        const ushort* vg = Vt + base + (long)srow * L_SEQ + scol;
        va = *(const uint4*)vg; vb = *(const uint4*)(vg + 8);
    }

    for (int kv0 = 0; kv0 <= q0; kv0 += 64) {
        __syncthreads();
        *(uint4*)(Ksh + srow * KP + scol)     = ka;
        *(uint4*)(Ksh + srow * KP + scol + 8) = kb;
        *(uint4*)(Vsh + srow * KP + scol)     = va;
        *(uint4*)(Vsh + srow * KP + scol + 8) = vb;
        __syncthreads();
        if (kv0 + 64 <= q0) {   // prefetch next tile; latency hidden by compute
            const ushort* kg = Kr + base + (long)(kv0 + 64 + srow) * HDIM + scol;
            ka = *(const uint4*)kg; kb = *(const uint4*)(kg + 8);
            const ushort* vg = Vt + base + (long)srow * L_SEQ + kv0 + 64 + scol;
            va = *(const uint4*)vg; vb = *(const uint4*)(vg + 8);
        }

        // S = Q K^T
        f32x4 s[4] = {};
#pragma unroll
        for (int nt = 0; nt < 4; nt++) {
            bf16x8 kf0 = *(const bf16x8*)(Ksh + (nt * 16 + l16) * KP + quad * 8);
            bf16x8 kf1 = *(const bf16x8*)(Ksh + (nt * 16 + l16) * KP + 32 + quad * 8);
            s[nt] = __builtin_amdgcn_mfma_f32_16x16x32_bf16(qf0, kf0, s[nt], 0, 0, 0);
            s[nt] = __builtin_amdgcn_mfma_f32_16x16x32_bf16(qf1, kf1, s[nt], 0, 0, 0);
        }

        // fixed-max softmax: p = exp2(s); diagonal causal mask by select
        const bool diag = (kv0 == q0);
#pragma unroll
        for (int nt = 0; nt < 4; nt++) {
            const int col = nt * 16 + l16;
#pragma unroll
            for (int r = 0; r < 4; r++) {
                float p = __builtin_exp2f(s[nt][r]);
                if (diag && col > row_l + r) p = 0.f;
                lr[r] += p;
                Psh[wave][(quad * 4 + r) * KP + col] = f2bf_t(p);
            }
        }

        // PV (compiler inserts lgkmcnt between P writes and these reads)
#pragma unroll
        for (int ks = 0; ks < 2; ks++) {
            bf16x8 pf = *(const bf16x8*)(&Psh[wave][l16 * KP + ks * 32 + quad * 8]);
#pragma unroll
            for (int nt = 0; nt < 4; nt++) {
                bf16x8 vf = *(const bf16x8*)(Vsh + (nt * 16 + l16) * KP + ks * 32 + quad * 8);
                o[nt] = __builtin_amdgcn_mfma_f32_16x16x32_bf16(pf, vf, o[nt], 0, 0, 0);
            }
        }
    }

    // epilogue: reduce l over the 16 lanes sharing each row, normalize, store
    const int b = bh >> 5, h = bh & 31;
#pragma unroll
    for (int r = 0; r < 4; r++) {
        float a = lr[r];
        a += __shfl_xor(a, 1); a += __shfl_xor(a, 2); a += __shfl_xor(a, 4); a += __shfl_xor(a, 8);
        float inv = 1.f / a;
        long orow = (long)(b * L_SEQ + q0 + wave * 16 + quad * 4 + r) * HID + h * 64;
#pragma unroll
        for (int nt = 0; nt < 4; nt++)
            Oa[orow + nt * 16 + l16] = f2bf(o[nt][r] * inv);
    }
}

// ---------------- host launch ----------------
extern "C" void kernel_launch(void* const* d_in, const int* in_sizes, int n_in,
                              void* d_out, int out_size, void* d_ws, size_t ws_size,
                              hipStream_t stream) {
    const float* hs     = (const float*)d_in[0];
    const float* prev_k = (const float*)d_in[1];
    const float* prev_v = (const float*)d_in[2];
    const float* Wq     = (const float*)d_in[3];
    const float* Wk     = (const float*)d_in[4];
    const float* Wv     = (const float*)d_in[5];
    const float* Wo     = (const float*)d_in[6];
    const float* cosb   = (const float*)d_in[7];
    const float* sinb   = (const float*)d_in[8];
    float* out = (float*)d_out;

    ushort* hs_bf   = (ushort*)d_ws;                 // 2048*2048
    ushort* wqkv_bf = hs_bf + 2048L * 2048;          // 2560*2048
    ushort* wo_bf   = wqkv_bf + 2560L * 2048;        // 2048*2048
    ushort* proj    = wo_bf + 2048L * 2048;          // 2048*2560
    ushort* Qr      = proj + 2048L * 2560;           // 2*32*1024*64
    ushort* Kr      = Qr + 4194304;
    ushort* Vt      = Kr + 4194304;
    ushort* Oa      = Vt + 4194304;                  // 2048*2048

    cvt_all<<<13312, 256, 0, stream>>>(hs, Wq, Wk, Wv, Wo,
                                       hs_bf, wqkv_bf,
                                       wqkv_bf + 2048L * 2048,
                                       wqkv_bf + 2304L * 2048,
                                       wo_bf);
    gemm_bt<true><<<dim3(20, 32), 256, 0, stream>>>(hs_bf, wqkv_bf, proj, 2048, 2560, 2048);
    prep_qkv<<<dim3(16, 64), 256, 0, stream>>>(proj, prev_k, prev_v, cosb, sinb, Qr, Kr, Vt);
    attn_mfma<<<dim3(16, 64), 256, 0, stream>>>(Qr, Kr, Vt, Oa);
    gemm_bt<false><<<dim3(16, 32), 256, 0, stream>>>(Oa, wo_bf, out, 2048, 2048, 2048);
}

// Round 9
// 237.042 us; speedup vs baseline: 1.3290x; 1.0168x over previous
//
#include <hip/hip_runtime.h>
#include <stdint.h>

#define L_SEQ 1024
#define NHEAD 32
#define NPREV 28
#define HDIM  64
#define HID   2048
#define NPROJ 2560  // 2048 q + 256 k + 256 v

typedef __bf16 bf16_t;
typedef bf16_t bf16x8 __attribute__((ext_vector_type(8)));
typedef float  f32x4  __attribute__((ext_vector_type(4)));

__device__ __forceinline__ ushort f2bf(float x) {
    union { float f; uint32_t u; } v; v.f = x;
    uint32_t r = v.u + 0x7fffu + ((v.u >> 16) & 1u);
    return (ushort)(r >> 16);
}
__device__ __forceinline__ ushort f2bf_t(float x) {  // truncate (cheap, P in [0,~150])
    union { float f; uint32_t u; } v; v.f = x;
    return (ushort)(v.u >> 16);
}
__device__ __forceinline__ float bf2f(ushort u) {
    union { uint32_t u; float f; } v; v.u = ((uint32_t)u) << 16; return v.f;
}
__device__ __forceinline__ void cvt8(float* dst, uint4 u) {
    union { uint32_t u; float f; } t;
    t.u = u.x << 16;         dst[0] = t.f;
    t.u = u.x & 0xffff0000u; dst[1] = t.f;
    t.u = u.y << 16;         dst[2] = t.f;
    t.u = u.y & 0xffff0000u; dst[3] = t.f;
    t.u = u.z << 16;         dst[4] = t.f;
    t.u = u.z & 0xffff0000u; dst[5] = t.f;
    t.u = u.w << 16;         dst[6] = t.f;
    t.u = u.w & 0xffff0000u; dst[7] = t.f;
}

#define GLB(p) ((const __attribute__((address_space(1))) void*)(p))
#define LDS(p) ((__attribute__((address_space(3))) void*)(p))

// ---------------- merged fp32 -> bf16 conversion ----------------
__global__ void cvt_all(const float* __restrict__ s0, const float* __restrict__ s1,
                        const float* __restrict__ s2, const float* __restrict__ s3,
                        const float* __restrict__ s4,
                        ushort* __restrict__ d0, ushort* __restrict__ d1,
                        ushort* __restrict__ d2, ushort* __restrict__ d3,
                        ushort* __restrict__ d4) {
    int blk = blockIdx.x;
    const float* src; ushort* dst; int idx;
    if      (blk < 4096) { src = s0; dst = d0; idx = blk; }
    else if (blk < 8192) { src = s1; dst = d1; idx = blk - 4096; }
    else if (blk < 8704) { src = s2; dst = d2; idx = blk - 8192; }
    else if (blk < 9216) { src = s3; dst = d3; idx = blk - 8704; }
    else                 { src = s4; dst = d4; idx = blk - 9216; }
    int i = idx * 256 + threadIdx.x;
    float4 v = ((const float4*)src)[i];
    ushort4 o;
    o.x = f2bf(v.x); o.y = f2bf(v.y); o.z = f2bf(v.z); o.w = f2bf(v.w);
    ((ushort4*)dst)[i] = o;
}

// ---------------- bf16 GEMM: C[M,N] = A[M,K] * B[N,K]^T ----------------
// 64x64 tile, 4 waves 2x2 (wave = 32x32), BK=64, global_load_lds width-16,
// LDS double-buffer (32 KB), single barrier per K-iter, 5 blocks/CU.
// XOR-swizzled LDS: staging position c of row rr holds global chunk
// c ^ ((rr>>1)&3); readers use chunk quad ^ ((l16>>1)&3) (free 2-way, m136).
template <bool OUT_BF16>
__global__ __launch_bounds__(256, 5) void gemm_bt(const ushort* __restrict__ A,
                                                  const ushort* __restrict__ B,
                                                  void* __restrict__ C,
                                                  int M, int N, int K) {
    __shared__ __align__(16) ushort Ash[2 * 4096];   // 2 bufs x (2 k-halves x 64x32)
    __shared__ __align__(16) ushort Bsh[2 * 4096];
    const int tid  = threadIdx.x;
    const int lane = tid & 63;
    const int wave = tid >> 6;
    const int quad = lane >> 4;
    const int l16  = lane & 15;
    const int m0 = blockIdx.y * 64;
    const int n0 = blockIdx.x * 64;
    const int wm = (wave >> 1) * 32;
    const int wn = (wave & 1) * 32;

    f32x4 acc[2][2] = {};

    // swizzled staging: chunk (row=tid>>2, c=tid&3) holds global colblock c^((row>>1)&3)
    const int sb = ((tid & 3) ^ ((tid >> 3) & 3)) * 8;
    const ushort* Ag = A + (long)(m0 + (tid >> 2)) * K + sb;
    const ushort* Bg = B + (long)(n0 + (tid >> 2)) * K + sb;
    const int woff = wave * 512;
    const int swz = (quad ^ ((l16 >> 1) & 3)) * 8;   // reader chunk select

    // preload k=[0,64) into buf 0 (regions: [khalf 2048][row*32 + chunk*8])
    __builtin_amdgcn_global_load_lds(GLB(Ag),      LDS(Ash + woff),        16, 0, 0);
    __builtin_amdgcn_global_load_lds(GLB(Ag + 32), LDS(Ash + 2048 + woff), 16, 0, 0);
    __builtin_amdgcn_global_load_lds(GLB(Bg),      LDS(Bsh + woff),        16, 0, 0);
    __builtin_amdgcn_global_load_lds(GLB(Bg + 32), LDS(Bsh + 2048 + woff), 16, 0, 0);

    int cur = 0;
    for (int k0 = 0; k0 < K; k0 += 64) {
        __syncthreads();   // drains vmcnt -> buf[cur] ready
        if (k0 + 64 < K) {
            const int nx = (cur ^ 1) * 4096;
            const ushort* Agn = Ag + k0 + 64;
            const ushort* Bgn = Bg + k0 + 64;
            __builtin_amdgcn_global_load_lds(GLB(Agn),      LDS(Ash + nx + woff),        16, 0, 0);
            __builtin_amdgcn_global_load_lds(GLB(Agn + 32), LDS(Ash + nx + 2048 + woff), 16, 0, 0);
            __builtin_amdgcn_global_load_lds(GLB(Bgn),      LDS(Bsh + nx + woff),        16, 0, 0);
            __builtin_amdgcn_global_load_lds(GLB(Bgn + 32), LDS(Bsh + nx + 2048 + woff), 16, 0, 0);
        }
        const ushort* As = Ash + cur * 4096;
        const ushort* Bs = Bsh + cur * 4096;
#pragma unroll
        for (int h = 0; h < 2; h++) {
            bf16x8 af[2], bf[2];
#pragma unroll
            for (int i = 0; i < 2; i++) {
                af[i] = *(const bf16x8*)(As + h * 2048 + (wm + i * 16 + l16) * 32 + swz);
                bf[i] = *(const bf16x8*)(Bs + h * 2048 + (wn + i * 16 + l16) * 32 + swz);
            }
#pragma unroll
            for (int mi = 0; mi < 2; mi++)
#pragma unroll
                for (int ni = 0; ni < 2; ni++)
                    acc[mi][ni] = __builtin_amdgcn_mfma_f32_16x16x32_bf16(af[mi], bf[ni], acc[mi][ni], 0, 0, 0);
        }
        cur ^= 1;
    }
#pragma unroll
    for (int mi = 0; mi < 2; mi++)
#pragma unroll
        for (int ni = 0; ni < 2; ni++)
#pragma unroll
            for (int r = 0; r < 4; r++) {
                int m = m0 + wm + mi * 16 + quad * 4 + r;
                int n = n0 + wn + ni * 16 + l16;
                float v = acc[mi][ni][r];
                if (OUT_BF16) ((ushort*)C)[(long)m * N + n] = f2bf(v);
                else          ((float*)C)[(long)m * N + n]  = v;
            }
}

// ---------------- prep: DeCAN gather + RoPE + V transpose fused ----------------
__global__ __launch_bounds__(256) void prep_qkv(const ushort* __restrict__ proj,
                                                const float* __restrict__ prev_k,
                                                const float* __restrict__ prev_v,
                                                const float* __restrict__ cosb,
                                                const float* __restrict__ sinb,
                                                ushort* __restrict__ Qr,
                                                ushort* __restrict__ Kr,
                                                ushort* __restrict__ Vt) {
    __shared__ __align__(16) ushort T[64 * 72];
    const int t  = threadIdx.x;
    const int l0 = blockIdx.x * 64;
    const int bh = blockIdx.y;
    const int b  = bh >> 5, h = bh & 31;
    const int r  = t >> 2;
    const int c0 = (t & 3) * 8;
    const int l  = l0 + r;
    const long prow = ((long)(b * L_SEQ + l)) * NPROJ;
    const long base = (long)bh * (L_SEQ * HDIM);

    float cv[8], sv[8];
    *(float4*)(cv)     = *(const float4*)(cosb + l * 64 + c0);
    *(float4*)(cv + 4) = *(const float4*)(cosb + l * 64 + c0 + 4);
    *(float4*)(sv)     = *(const float4*)(sinb + l * 64 + c0);
    *(float4*)(sv + 4) = *(const float4*)(sinb + l * 64 + c0 + 4);

    const float SC = 0.125f * 1.44269504f;  // scale * log2(e)

    // ---- Q ----
    {
        float xl[8], xh[8];
        cvt8(xl, *(const uint4*)(proj + prow + h * 64 + c0));
        cvt8(xh, *(const uint4*)(proj + prow + h * 64 + c0 + 32));
        ushort ol[8], oh[8];
#pragma unroll
        for (int i = 0; i < 8; i++) {
            ol[i] = f2bf((xl[i] * cv[i] - xh[i] * sv[i]) * SC);
            oh[i] = f2bf((xh[i] * cv[i] + xl[i] * sv[i]) * SC);
        }
        ushort* q = Qr + base + (long)l * 64;
        *(uint4*)(q + c0)      = *(uint4*)ol;
        *(uint4*)(q + c0 + 32) = *(uint4*)oh;
    }
    // ---- K ----
    {
        float xl[8], xh[8];
        if (h < NPREV) {
            const float* pk = prev_k + (((long)b * NPREV + h) * L_SEQ + l) * 64;
            *(float4*)(xl)     = *(const float4*)(pk + c0);
            *(float4*)(xl + 4) = *(const float4*)(pk + c0 + 4);
            *(float4*)(xh)     = *(const float4*)(pk + c0 + 32);
            *(float4*)(xh + 4) = *(const float4*)(pk + c0 + 36);
        } else {
            cvt8(xl, *(const uint4*)(proj + prow + HID + (h - NPREV) * 64 + c0));
            cvt8(xh, *(const uint4*)(proj + prow + HID + (h - NPREV) * 64 + c0 + 32));
        }
        ushort ol[8], oh[8];
#pragma unroll
        for (int i = 0; i < 8; i++) {
            ol[i] = f2bf(xl[i] * cv[i] - xh[i] * sv[i]);
            oh[i] = f2bf(xh[i] * cv[i] + xl[i] * sv[i]);
        }
        ushort* k = Kr + base + (long)l * 64;
        *(uint4*)(k + c0)      = *(uint4*)ol;
        *(uint4*)(k + c0 + 32) = *(uint4*)oh;
    }
    // ---- V (transpose via LDS) ----
    {
        float xl[8], xh[8];
        if (h < NPREV) {
            const float* pv = prev_v + (((long)b * NPREV + h) * L_SEQ + l) * 64;
            *(float4*)(xl)     = *(const float4*)(pv + c0);
            *(float4*)(xl + 4) = *(const float4*)(pv + c0 + 4);
            *(float4*)(xh)     = *(const float4*)(pv + c0 + 32);
            *(float4*)(xh + 4) = *(const float4*)(pv + c0 + 36);
        } else {
            cvt8(xl, *(const uint4*)(proj + prow + HID + 256 + (h - NPREV) * 64 + c0));
            cvt8(xh, *(const uint4*)(proj + prow + HID + 256 + (h - NPREV) * 64 + c0 + 32));
        }
#pragma unroll
        for (int i = 0; i < 8; i++) {
            T[(c0 + i) * 72 + r]      = f2bf(xl[i]);
            T[(c0 + 32 + i) * 72 + r] = f2bf(xh[i]);
        }
    }
    __syncthreads();
    {
        const int lc = (t & 3) * 16;
        uint4 o0 = *(const uint4*)(T + r * 72 + lc);
        uint4 o1 = *(const uint4*)(T + r * 72 + lc + 8);
        ushort* og = Vt + base + (long)r * L_SEQ + l0 + lc;
        *(uint4*)og       = o0;
        *(uint4*)(og + 8) = o1;
    }
}

// ---------------- MFMA flash attention v5 + XCD-local grid ----------------
// grid (64 bh, 16 qt): blocks of the same bh have flat IDs strided by 64
// (≡0 mod 8) -> same XCD under round-robin dispatch -> KV (256 KB/bh,
// 2 MB per XCD for 8 bh) stays L2-resident across all 16 q-tiles.
// Heavy-first via qt = 15 - blockIdx.y (heaviest q-tiles dispatch first).
// Compute structure identical to R8 (proven): shared-LDS K/V staging with
// register prefetch, 2 barriers/iter, fixed-max exp2 softmax, deferred l.
#define KP 68
__global__ __launch_bounds__(256, 4) void attn_mfma(const ushort* __restrict__ Qr,
                                                    const ushort* __restrict__ Kr,
                                                    const ushort* __restrict__ Vt,
                                                    ushort* __restrict__ Oa) {
    __shared__ __align__(16) ushort Ksh[64 * KP];
    __shared__ __align__(16) ushort Vsh[64 * KP];
    __shared__ __align__(16) ushort Psh[4][16 * KP];

    const int tid  = threadIdx.x;
    const int lane = tid & 63;
    const int wave = tid >> 6;
    const int quad = lane >> 4;
    const int l16  = lane & 15;
    const int bh   = blockIdx.x;
    const int q0   = (15 - (int)blockIdx.y) * 64;  // heavy q-tiles first
    const long base = (long)bh * (L_SEQ * HDIM);

    bf16x8 qf0, qf1;
    {
        const ushort* qp = Qr + base + (long)(q0 + wave * 16 + l16) * HDIM + quad * 8;
        qf0 = *(const bf16x8*)qp;
        qf1 = *(const bf16x8*)(qp + 32);
    }
    float lr[4] = {};            // per-lane partial row sums (deferred reduce)
    f32x4 o[4] = {};

    const int srow  = tid >> 2;
    const int scol  = (tid & 3) * 16;
    const int row_l = wave * 16 + quad * 4;   // q-row offset within block

    // prefetch tile 0
    uint4 ka, kb, va, vb;
    {
        const ushort* kg = Kr + base + (long)srow * HDIM + scol;
        ka = *(const uint4*)kg; kb = *(const uint4*)(kg + 8);
        const ushort* vg = Vt + base + (long)srow * L_SEQ + scol;
        va = *(const uint4*)vg; vb = *(const uint4*)(vg + 8);
    }

    for (int kv0 = 0; kv0 <= q0; kv0 += 64) {
        __syncthreads();
        *(uint4*)(Ksh + srow * KP + scol)     = ka;
        *(uint4*)(Ksh + srow * KP + scol + 8) = kb;
        *(uint4*)(Vsh + srow * KP + scol)     = va;
        *(uint4*)(Vsh + srow * KP + scol + 8) = vb;
        __syncthreads();
        if (kv0 + 64 <= q0) {   // prefetch next tile; latency hidden by compute
            const ushort* kg = Kr + base + (long)(kv0 + 64 + srow) * HDIM + scol;
            ka = *(const uint4*)kg; kb = *(const uint4*)(kg + 8);
            const ushort* vg = Vt + base + (long)srow * L_SEQ + kv0 + 64 + scol;
            va = *(const uint4*)vg; vb = *(const uint4*)(vg + 8);
        }

        // S = Q K^T
        f32x4 s[4] = {};
#pragma unroll
        for (int nt = 0; nt < 4; nt++) {
            bf16x8 kf0 = *(const bf16x8*)(Ksh + (nt * 16 + l16) * KP + quad * 8);
            bf16x8 kf1 = *(const bf16x8*)(Ksh + (nt * 16 + l16) * KP + 32 + quad * 8);
            s[nt] = __builtin_amdgcn_mfma_f32_16x16x32_bf16(qf0, kf0, s[nt], 0, 0, 0);
            s[nt] = __builtin_amdgcn_mfma_f32_16x16x32_bf16(qf1, kf1, s[nt], 0, 0, 0);
        }

        // fixed-max softmax: p = exp2(s); diagonal causal mask by select
        const bool diag = (kv0 == q0);
#pragma unroll
        for (int nt = 0; nt < 4; nt++) {
            const int col = nt * 16 + l16;
#pragma unroll
            for (int r = 0; r < 4; r++) {
                float p = __builtin_exp2f(s[nt][r]);
                if (diag && col > row_l + r) p = 0.f;
                lr[r] += p;
                Psh[wave][(quad * 4 + r) * KP + col] = f2bf_t(p);
            }
        }

        // PV (compiler inserts lgkmcnt between P writes and these reads)
#pragma unroll
        for (int ks = 0; ks < 2; ks++) {
            bf16x8 pf = *(const bf16x8*)(&Psh[wave][l16 * KP + ks * 32 + quad * 8]);
#pragma unroll
            for (int nt = 0; nt < 4; nt++) {
                bf16x8 vf = *(const bf16x8*)(Vsh + (nt * 16 + l16) * KP + ks * 32 + quad * 8);
                o[nt] = __builtin_amdgcn_mfma_f32_16x16x32_bf16(pf, vf, o[nt], 0, 0, 0);
            }
        }
    }

    // epilogue: reduce l over the 16 lanes sharing each row, normalize, store
    const int b = bh >> 5, h = bh & 31;
#pragma unroll
    for (int r = 0; r < 4; r++) {
        float a = lr[r];
        a += __shfl_xor(a, 1); a += __shfl_xor(a, 2); a += __shfl_xor(a, 4); a += __shfl_xor(a, 8);
        float inv = 1.f / a;
        long orow = (long)(b * L_SEQ + q0 + wave * 16 + quad * 4 + r) * HID + h * 64;
#pragma unroll
        for (int nt = 0; nt < 4; nt++)
            Oa[orow + nt * 16 + l16] = f2bf(o[nt][r] * inv);
    }
}

// ---------------- host launch ----------------
extern "C" void kernel_launch(void* const* d_in, const int* in_sizes, int n_in,
                              void* d_out, int out_size, void* d_ws, size_t ws_size,
                              hipStream_t stream) {
    const float* hs     = (const float*)d_in[0];
    const float* prev_k = (const float*)d_in[1];
    const float* prev_v = (const float*)d_in[2];
    const float* Wq     = (const float*)d_in[3];
    const float* Wk     = (const float*)d_in[4];
    const float* Wv     = (const float*)d_in[5];
    const float* Wo     = (const float*)d_in[6];
    const float* cosb   = (const float*)d_in[7];
    const float* sinb   = (const float*)d_in[8];
    float* out = (float*)d_out;

    ushort* hs_bf   = (ushort*)d_ws;                 // 2048*2048
    ushort* wqkv_bf = hs_bf + 2048L * 2048;          // 2560*2048
    ushort* wo_bf   = wqkv_bf + 2560L * 2048;        // 2048*2048
    ushort* proj    = wo_bf + 2048L * 2048;          // 2048*2560
    ushort* Qr      = proj + 2048L * 2560;           // 2*32*1024*64
    ushort* Kr      = Qr + 4194304;
    ushort* Vt      = Kr + 4194304;
    ushort* Oa      = Vt + 4194304;                  // 2048*2048

    cvt_all<<<13312, 256, 0, stream>>>(hs, Wq, Wk, Wv, Wo,
                                       hs_bf, wqkv_bf,
                                       wqkv_bf + 2048L * 2048,
                                       wqkv_bf + 2304L * 2048,
                                       wo_bf);
    gemm_bt<true><<<dim3(40, 32), 256, 0, stream>>>(hs_bf, wqkv_bf, proj, 2048, 2560, 2048);
    prep_qkv<<<dim3(16, 64), 256, 0, stream>>>(proj, prev_k, prev_v, cosb, sinb, Qr, Kr, Vt);
    attn_mfma<<<dim3(64, 16), 256, 0, stream>>>(Qr, Kr, Vt, Oa);
    gemm_bt<false><<<dim3(32, 32), 256, 0, stream>>>(Oa, wo_bf, out, 2048, 2048, 2048);
}